// Round 8
// baseline (454.813 us; speedup 1.0000x reference)
//
#include <hip/hip_runtime.h>

#define RNN_T 2048
#define RNN_B 4096
#define BLK 16                 // timesteps per staged block
#define NBLK (RNN_T / BLK)     // 128
#define CHF (BLK * 5)          // 80 floats per chain per block
#define WVF (8 * CHF)          // 640 floats per wave per block (8 chains)
#define BLF (4 * WVF)          // 2560 floats per 256-thr block buffer

// tanh with pre-scaled argument: zs = 2*log2(e)*z ; tanh(z) = 1 - 2/(1 + 2^zs)
__device__ __forceinline__ float tanh_pre(float zs) {
    float e = __builtin_amdgcn_exp2f(zs);
    float r = __builtin_amdgcn_rcpf(e + 1.0f);
    return fmaf(-2.0f, r, 1.0f);
}

// Async global->LDS, 4B per lane, dest = wave-uniform base + lane*4.
__device__ __forceinline__ void async4(const float* src, float* dst) {
    __builtin_amdgcn_global_load_lds(
        (const __attribute__((address_space(1))) void*)src,
        (__attribute__((address_space(3))) void*)dst, 4, 0, 0);
}

// Fill one wave's 640-float region (8 chains x 80) = 10 DMA instructions.
__device__ __forceinline__ void fill_wave(float* dstWave, const float* (&src)[10],
                                          int adv) {
#pragma unroll
    for (int j = 0; j < 10; ++j) {
        async4(src[j], dstWave + j * 64);
        src[j] += adv;
    }
}

// Pair-interleaved 16-ring: each 16-lane row hosts 2 chains (even/odd lanes).
// Lane (par, c0=l16>>1) holds s0 = comp c0 (h0..h7), s1 = comp 8+c0
// (h8 for c0=0; x[c0-1] for c0 in [1,6); junk for c0=6,7).
// row_ror:2r preserves parity: delivers comp ((c0-r)&7) + 8j from reg j.
// Lane computes rows c0 (->s0) and 8+c0 (real only c0=0 -> s1).
__device__ __forceinline__ void stepB(float& s0, float& s1, float xn,
        const float (&Wa)[16], const float (&Wb)[16],
        float bb0, float bb1, bool own8) {
    float a0 = fmaf(s0, Wa[0], bb0);   // row c0,  j=0, rot 0
    float a1 = s1 * Wa[8];             // row c0,  j=1, rot 0
    float b0 = fmaf(s0, Wb[0], bb1);   // row 8+c0, j=0, rot 0
    float b1 = s1 * Wb[8];             // row 8+c0, j=1, rot 0
    asm("s_nop 1\n\t"
        "v_fmac_f32_dpp %0, %2, %4  row_ror:2  row_mask:0xf bank_mask:0xf\n\t"
        "v_fmac_f32_dpp %1, %3, %11 row_ror:2  row_mask:0xf bank_mask:0xf\n\t"
        "v_fmac_f32_dpp %0, %2, %5  row_ror:4  row_mask:0xf bank_mask:0xf\n\t"
        "v_fmac_f32_dpp %1, %3, %12 row_ror:4  row_mask:0xf bank_mask:0xf\n\t"
        "v_fmac_f32_dpp %0, %2, %6  row_ror:6  row_mask:0xf bank_mask:0xf\n\t"
        "v_fmac_f32_dpp %1, %3, %13 row_ror:6  row_mask:0xf bank_mask:0xf\n\t"
        "v_fmac_f32_dpp %0, %2, %7  row_ror:8  row_mask:0xf bank_mask:0xf\n\t"
        "v_fmac_f32_dpp %1, %3, %14 row_ror:8  row_mask:0xf bank_mask:0xf\n\t"
        "v_fmac_f32_dpp %0, %2, %8  row_ror:10 row_mask:0xf bank_mask:0xf\n\t"
        "v_fmac_f32_dpp %1, %3, %15 row_ror:10 row_mask:0xf bank_mask:0xf\n\t"
        "v_fmac_f32_dpp %0, %2, %9  row_ror:12 row_mask:0xf bank_mask:0xf\n\t"
        "v_fmac_f32_dpp %1, %3, %16 row_ror:12 row_mask:0xf bank_mask:0xf\n\t"
        "v_fmac_f32_dpp %0, %2, %10 row_ror:14 row_mask:0xf bank_mask:0xf\n\t"
        "v_fmac_f32_dpp %1, %3, %17 row_ror:14 row_mask:0xf bank_mask:0xf"
        : "+v"(a0), "+v"(a1)
        : "v"(s0), "v"(s1),
          "v"(Wa[1]), "v"(Wa[2]), "v"(Wa[3]), "v"(Wa[4]), "v"(Wa[5]),
          "v"(Wa[6]), "v"(Wa[7]),
          "v"(Wa[9]), "v"(Wa[10]), "v"(Wa[11]), "v"(Wa[12]), "v"(Wa[13]),
          "v"(Wa[14]), "v"(Wa[15]));
    asm("s_nop 1\n\t"
        "v_fmac_f32_dpp %0, %2, %4  row_ror:2  row_mask:0xf bank_mask:0xf\n\t"
        "v_fmac_f32_dpp %1, %3, %11 row_ror:2  row_mask:0xf bank_mask:0xf\n\t"
        "v_fmac_f32_dpp %0, %2, %5  row_ror:4  row_mask:0xf bank_mask:0xf\n\t"
        "v_fmac_f32_dpp %1, %3, %12 row_ror:4  row_mask:0xf bank_mask:0xf\n\t"
        "v_fmac_f32_dpp %0, %2, %6  row_ror:6  row_mask:0xf bank_mask:0xf\n\t"
        "v_fmac_f32_dpp %1, %3, %13 row_ror:6  row_mask:0xf bank_mask:0xf\n\t"
        "v_fmac_f32_dpp %0, %2, %7  row_ror:8  row_mask:0xf bank_mask:0xf\n\t"
        "v_fmac_f32_dpp %1, %3, %14 row_ror:8  row_mask:0xf bank_mask:0xf\n\t"
        "v_fmac_f32_dpp %0, %2, %8  row_ror:10 row_mask:0xf bank_mask:0xf\n\t"
        "v_fmac_f32_dpp %1, %3, %15 row_ror:10 row_mask:0xf bank_mask:0xf\n\t"
        "v_fmac_f32_dpp %0, %2, %9  row_ror:12 row_mask:0xf bank_mask:0xf\n\t"
        "v_fmac_f32_dpp %1, %3, %16 row_ror:12 row_mask:0xf bank_mask:0xf\n\t"
        "v_fmac_f32_dpp %0, %2, %10 row_ror:14 row_mask:0xf bank_mask:0xf\n\t"
        "v_fmac_f32_dpp %1, %3, %17 row_ror:14 row_mask:0xf bank_mask:0xf"
        : "+v"(b0), "+v"(b1)
        : "v"(s0), "v"(s1),
          "v"(Wb[1]), "v"(Wb[2]), "v"(Wb[3]), "v"(Wb[4]), "v"(Wb[5]),
          "v"(Wb[6]), "v"(Wb[7]),
          "v"(Wb[9]), "v"(Wb[10]), "v"(Wb[11]), "v"(Wb[12]), "v"(Wb[13]),
          "v"(Wb[14]), "v"(Wb[15]));
    const float z0 = a0 + a1;
    const float z1 = b0 + b1;
    const float t1 = tanh_pre(z1);
    s0 = tanh_pre(z0);
    s1 = own8 ? t1 : xn;   // c0==0: h8; else next x (finite junk for c0>=6)
}

// 16 steps from xc (per-lane base includes component offset cx).
template <bool FWD, bool FILL>
__device__ __forceinline__ void compute_block(const float* xc, const float* xnb,
        float& s0, float& s1, const float (&Wa)[16], const float (&Wb)[16],
        float bb0, float bb1, bool own8,
        float* fillDst, const float* (&src)[10], int adv) {
    float xn[16];
#pragma unroll
    for (int j = 0; j < 15; ++j) xn[j] = xc[FWD ? (j + 1) * 5 : (14 - j) * 5];
    xn[15] = xnb[FWD ? 0 : 75];
    if constexpr (FILL) fill_wave(fillDst, src, adv);
#pragma unroll
    for (int j = 0; j < 16; ++j)
        stepB(s0, s1, xn[j], Wa, Wb, bb0, bb1, own8);
}

// Triple-buffered rotation (statically distinct __shared__ objects).
template <bool FWD>
__device__ __forceinline__ void run_all(const float* xcA, const float* xcB,
        const float* xcC, float* wA, float* wB, float* wC,
        const float* (&src)[10], int adv,
        const float (&Wa)[16], const float (&Wb)[16], float bb0, float bb1,
        bool own8, float& s0, float& s1) {
    fill_wave(wA, src, adv);   // block 0
    fill_wave(wB, src, adv);   // block 1
    s0 = 0.0f;
    const float pr = xcA[FWD ? 0 : 75];   // first x (waits on fill A)
    s1 = own8 ? 0.0f : pr;
#pragma unroll 1
    for (int it = 0; it < 42; ++it) {   // blocks 3k,3k+1,3k+2 (0..125)
        compute_block<FWD, true >(xcA, xcB, s0, s1, Wa, Wb, bb0, bb1, own8, wC, src, adv);
        compute_block<FWD, true >(xcB, xcC, s0, s1, Wa, Wb, bb0, bb1, own8, wA, src, adv);
        compute_block<FWD, true >(xcC, xcA, s0, s1, Wa, Wb, bb0, bb1, own8, wB, src, adv);
    }
    compute_block<FWD, false>(xcA, xcB, s0, s1, Wa, Wb, bb0, bb1, own8, wC, src, adv); // 126
    compute_block<FWD, false>(xcB, xcB, s0, s1, Wa, Wb, bb0, bb1, own8, wC, src, adv); // 127
}

__device__ __forceinline__ float wfull(const float* wih, const float* whh,
                                       int row, int c) {
    if (c < 9)  return whh[row * 9 + c];
    if (c < 14) return wih[row * 5 + (c - 9)];
    return 0.0f;
}

// 8 chains/wave (2 per 16-lane row, parity-interleaved); 256x256 = 1024 waves
// = 1 wave/SIMD machine-wide. x staged via LDS DMA (issue point pinned).
__global__ __launch_bounds__(256, 1) void rnn1_kernel(
    const float* __restrict__ x,
    const float* __restrict__ w_ih_f, const float* __restrict__ w_hh_f,
    const float* __restrict__ b_ih_f, const float* __restrict__ b_hh_f,
    const float* __restrict__ w_ih_b, const float* __restrict__ w_hh_b,
    const float* __restrict__ b_ih_b, const float* __restrict__ b_hh_b,
    float* __restrict__ y)
{
    __shared__ __align__(16) float sA[BLF], sB[BLF], sC[BLF];   // 3 x 10240 B
    const float SC = 2.8853900817779268f; // 2*log2(e)
    const int tid    = threadIdx.x;
    const int waveId = tid >> 6;          // 0..3
    const int lane   = tid & 63;
    const int l16    = lane & 15;
    const int row16  = lane >> 4;         // 0..3
    const int par    = l16 & 1;           // chain parity within the 16-row
    const int c0     = l16 >> 1;          // 0..7 (owned component index)
    const int chainL = row16 * 2 + par;   // 0..7 within wave
    const int chain  = blockIdx.x * 32 + waveId * 8 + chainL;  // 0..8191
    const int b      = chain & (RNN_B - 1);
    const int dir    = chain >> 12;       // uniform per block (128 blocks/dir)

    const float* __restrict__ wih = dir ? w_ih_b : w_ih_f;
    const float* __restrict__ whh = dir ? w_hh_b : w_hh_f;
    const float* __restrict__ bih = dir ? b_ih_b : b_ih_f;
    const float* __restrict__ bhh = dir ? b_hh_b : b_hh_f;

    // Weights: Wa = row c0 (always real), Wb = row 8+c0 (real only c0==0).
    // Index j*8+r: delivery of comp ((c0-r)&7)+8j under row_ror:2r on reg j.
    const bool own8 = (c0 == 0);
    float Wa[16], Wb[16];
#pragma unroll
    for (int j = 0; j < 2; ++j)
#pragma unroll
        for (int r = 0; r < 8; ++r) {
            const int c = ((c0 - r) & 7) + 8 * j;
            Wa[j * 8 + r] = wfull(wih, whh, c0, c) * SC;
            Wb[j * 8 + r] = own8 ? (wfull(wih, whh, 8, c) * SC) : 0.0f;
        }
    const float bb0 = (bih[c0] + bhh[c0]) * SC;
    const float bb1 = own8 ? ((bih[8] + bhh[8]) * SC) : 0.0f;

    // DMA source pointers: instr j covers wave-region word idx = j*64+lane:
    // chainLocal gf = idx/80, in-block pos p = idx%80.
    const float* src[10];
#pragma unroll
    for (int j = 0; j < 10; ++j) {
        const int idx = j * 64 + lane;            // 0..639
        const int gf  = idx / 80;                 // 0..7
        const int p   = idx - gf * 80;
        const int bf  = (blockIdx.x * 32 + waveId * 8 + gf) & (RNN_B - 1);
        src[j] = x + (size_t)bf * (RNN_T * 5) + (dir ? (NBLK - 1) * CHF : 0) + p;
    }
    const int adv = dir ? -CHF : CHF;

    float* wA = sA + waveId * WVF;
    float* wB = sB + waveId * WVF;
    float* wC = sC + waveId * WVF;
    // Per-lane x-read base: component cx = c0-1 for c0 in [1,6), else 0 (dummy).
    const int cx = (c0 >= 1 && c0 <= 5) ? (c0 - 1) : 0;
    const float* xcA = sA + waveId * WVF + chainL * CHF + cx;
    const float* xcB = sB + waveId * WVF + chainL * CHF + cx;
    const float* xcC = sC + waveId * WVF + chainL * CHF + cx;

    float s0, s1;
    if (dir) run_all<false>(xcA, xcB, xcC, wA, wB, wC, src, adv,
                            Wa, Wb, bb0, bb1, own8, s0, s1);
    else     run_all<true >(xcA, xcB, xcC, wA, wB, wC, src, adv,
                            Wa, Wb, bb0, bb1, own8, s0, s1);

    y[b * 18 + dir * 9 + c0] = s0;                  // comps 0..7
    if (l16 < 2) y[b * 18 + dir * 9 + 8] = s1;      // comp 8 (c0==0 lanes)
}

__global__ __launch_bounds__(256) void rnn2_kernel(
    const float* __restrict__ y,
    const float* __restrict__ w_ih2, const float* __restrict__ w_hh2,
    const float* __restrict__ b_ih2, const float* __restrict__ b_hh2,
    const float* __restrict__ w_out, const float* __restrict__ b_out,
    float* __restrict__ out)
{
    __shared__ float hist[8][25][32];   // 25.6 KB
    const float SC = 2.8853900817779268f;
    const int bl = threadIdx.x >> 5;    // 0..7 local batch
    const int i  = threadIdx.x & 31;    // component
    const int b  = blockIdx.x * 8 + bl;

    float wr[32];
#pragma unroll
    for (int k = 0; k < 32; ++k) wr[k] = w_hh2[i * 32 + k] * SC;
    const float bias = (b_ih2[i] + b_hh2[i]) * SC;

    const float* yb = y + b * 18;
    float z = bias;
#pragma unroll
    for (int k = 0; k < 18; ++k) z = fmaf(w_ih2[i * 18 + k] * SC, yb[k], z);
    hist[bl][0][i] = tanh_pre(z);
    __syncthreads();

    for (int t = 1; t < 25; ++t) {
        float zz = bias;
#pragma unroll
        for (int k = 0; k < 32; ++k) zz = fmaf(wr[k], hist[bl][t - 1][k], zz);
        hist[bl][t][i] = tanh_pre(zz);
        __syncthreads();
    }

    for (int e = threadIdx.x; e < 600; e += 256) {
        const int o  = e % 3;
        const int t  = (e / 3) % 25;
        const int b2 = e / 75;
        float acc = b_out[o];
#pragma unroll
        for (int k = 0; k < 32; ++k) acc = fmaf(w_out[o * 32 + k], hist[b2][t][k], acc);
        out[((size_t)(blockIdx.x * 8 + b2) * 25 + t) * 3 + o] = acc;
    }
}

extern "C" void kernel_launch(void* const* d_in, const int* in_sizes, int n_in,
                              void* d_out, int out_size, void* d_ws, size_t ws_size,
                              hipStream_t stream) {
    const float* x      = (const float*)d_in[0];
    const float* w_ih_f = (const float*)d_in[1];
    const float* w_hh_f = (const float*)d_in[2];
    const float* b_ih_f = (const float*)d_in[3];
    const float* b_hh_f = (const float*)d_in[4];
    const float* w_ih_b = (const float*)d_in[5];
    const float* w_hh_b = (const float*)d_in[6];
    const float* b_ih_b = (const float*)d_in[7];
    const float* b_hh_b = (const float*)d_in[8];
    const float* w_ih2  = (const float*)d_in[9];
    const float* w_hh2  = (const float*)d_in[10];
    const float* b_ih2  = (const float*)d_in[11];
    const float* b_hh2  = (const float*)d_in[12];
    const float* w_out  = (const float*)d_in[13];
    const float* b_out  = (const float*)d_in[14];

    float* y = (float*)d_ws;                 // [B][18] intermediate

    rnn1_kernel<<<dim3(256), dim3(256), 0, stream>>>(
        x, w_ih_f, w_hh_f, b_ih_f, b_hh_f,
        w_ih_b, w_hh_b, b_ih_b, b_hh_b, y);

    rnn2_kernel<<<dim3(RNN_B / 8), dim3(256), 0, stream>>>(
        y, w_ih2, w_hh2, b_ih2, b_hh2, w_out, b_out, (float*)d_out);
}